// Round 8
// baseline (298.484 us; speedup 1.0000x reference)
//
#include <hip/hip_runtime.h>
#include <hip/hip_cooperative_groups.h>

namespace cg = cooperative_groups;

#define NN 35

// ws layout (floats):
//   h1[35*512] | h2[35*256] | h3[35*128] | part2[64*35*256] | part3[128*35*128]
//   | fallback region (agg2,agg3,h2f,h3f)
// All partial slots are fully overwritten each launch (no zero-init needed).

// ======================= Cooperative mega-kernel =======================
// 256 blocks x 512 threads (1 block/CU, proven to launch cooperatively).
// NO global atomics: partial-sum stores + reduce phases. R7 counters showed
// WRITE_SIZE == atomic bytes exactly -> device-scope atomic RMWs at the HBM
// coherence point (64 same-address RMWs per (d,o) across 8 XCDs) were the
// ~100 us stall.
__global__ __launch_bounds__(512, 2)
void mega_kernel(const float* __restrict__ x,      // [35,1]
                 const float* __restrict__ ea,     // [1190,4]
                 const float* __restrict__ W1, const float* __restrict__ b1,
                 const float* __restrict__ root1, const float* __restrict__ bias1,
                 const float* __restrict__ W2, const float* __restrict__ b2,
                 const float* __restrict__ root2, const float* __restrict__ bias2,
                 const float* __restrict__ W3, const float* __restrict__ b3,
                 const float* __restrict__ root3, const float* __restrict__ bias3,
                 float* __restrict__ out,          // [35,35]
                 float* __restrict__ ws)
{
    cg::grid_group grid = cg::this_grid();
    float* h1    = ws;                      // 35*512 = 17920
    float* h2    = h1 + 35 * 512;           // 35*256 =  8960
    float* h3    = h2 + 35 * 256;           // 35*128 =  4480
    float* part2 = h3 + 35 * 128;           // 64 * 8960 = 573440
    float* part3 = part2 + 64 * 8960;       // 128 * 4480 = 573440

    const int b = blockIdx.x;               // 0..255
    const int t = threadIdx.x;              // 0..511
    const int gtid = b * 512 + t;

    __shared__ __align__(16) float hs[35][16];
    __shared__ __align__(16) float hs3[35][8];
    __shared__ float4 as[34];

    // ---------- Phase 0: layer 1 (1 -> 512) ----------
    if (gtid < 35 * 512) {
        const int d = gtid >> 9, o = gtid & 511;
        const float u0 = W1[o], u1 = W1[512 + o], u2 = W1[1024 + o], u3 = W1[1536 + o];
        const float bb = b1[o];
        float sum = 0.f;
#pragma unroll
        for (int s = 0; s < NN; ++s) {
            if (s == d) continue;
            const float4 a = ((const float4*)ea)[s * 34 + (d < s ? d : d - 1)];
            float w = fmaf(a.x, u0, fmaf(a.y, u1, fmaf(a.z, u2, fmaf(a.w, u3, bb))));
            sum = fmaf(x[s], fmaxf(w, 0.f), sum);
        }
        h1[gtid] = fmaxf(sum * (1.f / 34.f) + x[d] * root1[o] + bias1[o], 0.f);
    }
    grid.sync();

    // ---------- Phase 1e: layer 2 edge partials (512 -> 256), dst-major ----------
    // unit u = (d, chunk c of IC=16). threads: o = t&255, half = t>>8 (8 i's each)
    // store: part2[(c*2+half)*8960 + d*256 + o]  (coalesced, contention-free)
    for (int u = b; u < 35 * 32; u += 256) {
        const int d  = u >> 5;
        const int i0 = (u & 31) << 4;
        if (t < 140) {
            const int r = t >> 2, k = t & 3;
            const int s = (r < 34) ? (r + (r >= d ? 1 : 0)) : d;   // row 34 = d itself
            ((float4*)hs[r])[k] = ((const float4*)(h1 + s * 512 + i0))[k];
        }
        if (t >= 192 && t < 226) {
            const int j = t - 192;
            const int s = j + (j >= d ? 1 : 0);
            as[j] = ((const float4*)ea)[s * 34 + (d < s ? d : d - 1)];
        }
        __syncthreads();

        const int o = t & 255, half = t >> 8;
        const int ib = half * 8;
        float w0[8], w1r[8], w2r[8], w3r[8], bbr[8], rr[8];
#pragma unroll
        for (int i = 0; i < 8; ++i) {
            const size_t base = (size_t)(i0 + ib + i) * 256 + o;
            w0[i]  = W2[base];
            w1r[i] = W2[131072 + base];
            w2r[i] = W2[262144 + base];
            w3r[i] = W2[393216 + base];
            bbr[i] = b2[base];
            rr[i]  = root2[base];
        }
        float acc0 = 0.f, acc1 = 0.f;
#pragma unroll 2
        for (int j = 0; j < 34; ++j) {
            const float4 a  = as[j];
            const float4 h0 = ((const float4*)hs[j])[half * 2];
            const float4 h1v = ((const float4*)hs[j])[half * 2 + 1];
            const float hm[8] = {h0.x, h0.y, h0.z, h0.w, h1v.x, h1v.y, h1v.z, h1v.w};
#pragma unroll
            for (int i = 0; i < 4; ++i) {
                float w = fmaf(a.x, w0[i], fmaf(a.y, w1r[i],
                          fmaf(a.z, w2r[i], fmaf(a.w, w3r[i], bbr[i]))));
                acc0 = fmaf(hm[i], fmaxf(w, 0.f), acc0);
            }
#pragma unroll
            for (int i = 4; i < 8; ++i) {
                float w = fmaf(a.x, w0[i], fmaf(a.y, w1r[i],
                          fmaf(a.z, w2r[i], fmaf(a.w, w3r[i], bbr[i]))));
                acc1 = fmaf(hm[i], fmaxf(w, 0.f), acc1);
            }
        }
        // root contribution for this half's i's (row 34 = d's own features)
        const float4 r0 = ((const float4*)hs[34])[half * 2];
        const float4 r1 = ((const float4*)hs[34])[half * 2 + 1];
        const float rm[8] = {r0.x, r0.y, r0.z, r0.w, r1.x, r1.y, r1.z, r1.w};
        float racc = 0.f;
#pragma unroll
        for (int i = 0; i < 8; ++i) racc = fmaf(rm[i], rr[i], racc);

        const int slot = ((u & 31) << 1) + half;      // c*2 + half, 0..63
        part2[(size_t)slot * 8960 + d * 256 + o] = (acc0 + acc1) * (1.f / 34.f) + racc;
        __syncthreads();
    }
    grid.sync();

    // ---------- Phase 1r: reduce 64 slots -> h2 = relu(sum + bias2) ----------
    if (gtid < 8960) {
        const int o = gtid & 255;
        float s = 0.f;
#pragma unroll 8
        for (int sl = 0; sl < 64; ++sl)
            s += part2[(size_t)sl * 8960 + gtid];
        h2[gtid] = fmaxf(s + bias2[o], 0.f);
    }
    grid.sync();

    // ---------- Phase 2e: layer 3 edge partials (256 -> 128) ----------
    // unit u = (d, chunk c of IC=8). threads: o = t&127, grp = t>>7 (j-groups 9/9/8/8)
    // store: part3[(c*4+grp)*4480 + d*128 + o]
    for (int u = b; u < 35 * 32; u += 256) {
        const int d  = u >> 5;
        const int i0 = (u & 31) << 3;
        if (t < 70) {
            const int r = t >> 1, k = t & 1;
            const int s = (r < 34) ? (r + (r >= d ? 1 : 0)) : d;
            ((float4*)hs3[r])[k] = ((const float4*)(h2 + s * 256 + i0))[k];
        }
        if (t >= 128 && t < 162) {
            const int j = t - 128;
            const int s = j + (j >= d ? 1 : 0);
            as[j] = ((const float4*)ea)[s * 34 + (d < s ? d : d - 1)];
        }
        __syncthreads();

        const int o = t & 127, grp = t >> 7;
        const int jstart = (grp < 2) ? grp * 9 : 18 + (grp - 2) * 8;
        const int jcnt   = (grp < 2) ? 9 : 8;

        float w0[8], w1r[8], w2r[8], w3r[8], bbr[8], rr[8];
#pragma unroll
        for (int i = 0; i < 8; ++i) {
            const size_t base = (size_t)(i0 + i) * 128 + o;
            w0[i]  = W3[base];
            w1r[i] = W3[32768 + base];
            w2r[i] = W3[65536 + base];
            w3r[i] = W3[98304 + base];
            bbr[i] = b3[base];
            rr[i]  = root3[base];
        }
        float acc0 = 0.f, acc1 = 0.f;
#pragma unroll 2
        for (int jj = 0; jj < jcnt; ++jj) {
            const int j = jstart + jj;
            const float4 a  = as[j];
            const float4 h0 = ((const float4*)hs3[j])[0];
            const float4 h1v = ((const float4*)hs3[j])[1];
            const float hm[8] = {h0.x, h0.y, h0.z, h0.w, h1v.x, h1v.y, h1v.z, h1v.w};
#pragma unroll
            for (int i = 0; i < 4; ++i) {
                float w = fmaf(a.x, w0[i], fmaf(a.y, w1r[i],
                          fmaf(a.z, w2r[i], fmaf(a.w, w3r[i], bbr[i]))));
                acc0 = fmaf(hm[i], fmaxf(w, 0.f), acc0);
            }
#pragma unroll
            for (int i = 4; i < 8; ++i) {
                float w = fmaf(a.x, w0[i], fmaf(a.y, w1r[i],
                          fmaf(a.z, w2r[i], fmaf(a.w, w3r[i], bbr[i]))));
                acc1 = fmaf(hm[i], fmaxf(w, 0.f), acc1);
            }
        }
        float contrib = (acc0 + acc1) * (1.f / 34.f);
        if (grp == 0) {                       // root contribution once per (d,c,o)
            const float4 r0 = ((const float4*)hs3[34])[0];
            const float4 r1 = ((const float4*)hs3[34])[1];
            const float rm[8] = {r0.x, r0.y, r0.z, r0.w, r1.x, r1.y, r1.z, r1.w};
            float racc = 0.f;
#pragma unroll
            for (int i = 0; i < 8; ++i) racc = fmaf(rm[i], rr[i], racc);
            contrib += racc;
        }
        const int slot = ((u & 31) << 2) + grp;       // c*4 + grp, 0..127
        part3[(size_t)slot * 4480 + d * 128 + o] = contrib;
        __syncthreads();
    }
    grid.sync();

    // ---------- Phase 2r: reduce 128 slots -> h3 = relu(sum + bias3) ----------
    if (gtid < 4480) {
        const int o = gtid & 127;
        float s = 0.f;
#pragma unroll 8
        for (int sl = 0; sl < 128; ++sl)
            s += part3[(size_t)sl * 4480 + gtid];
        h3[gtid] = fmaxf(s + bias3[o], 0.f);
    }
    grid.sync();

    // ---------- Phase 3: pairwise L1, one wave per (a,i) pair ----------
    {
        const int lane = t & 63;
        for (int wv = b * 8 + (t >> 6); wv < NN * NN; wv += 256 * 8) {
            const int a_ = wv / NN, i_ = wv % NN;
            float s = 0.f;
#pragma unroll
            for (int q = 0; q < 2; ++q) {
                const int f = lane + q * 64;
                s += fabsf(h3[i_ * 128 + f] - h3[a_ * 128 + f]);
            }
#pragma unroll
            for (int off = 32; off > 0; off >>= 1)
                s += __shfl_xor(s, off, 64);
            if (lane == 0) out[wv] = s;
        }
    }
}

// ======================= Fallback path (R4-proven) =======================
__global__ __launch_bounds__(512)
void layer1_kernel(const float* __restrict__ x, const float* __restrict__ ea,
                   const float* __restrict__ W1, const float* __restrict__ b1,
                   const float* __restrict__ root1, const float* __restrict__ bias1,
                   float* __restrict__ h1)
{
    const int d = blockIdx.x;
    const int o = threadIdx.x;
    const float w0 = W1[o], w1 = W1[512 + o], w2 = W1[1024 + o], w3 = W1[1536 + o];
    const float bb = b1[o];
    float sum = 0.f;
#pragma unroll
    for (int s = 0; s < NN; ++s) {
        if (s == d) continue;
        const float4 a = ((const float4*)ea)[s * 34 + (d < s ? d : d - 1)];
        float w = fmaf(a.x, w0, fmaf(a.y, w1, fmaf(a.z, w2, fmaf(a.w, w3, bb))));
        sum = fmaf(x[s], fmaxf(w, 0.f), sum);
    }
    h1[d * 512 + o] = fmaxf(sum / 34.f + x[d] * root1[o] + bias1[o], 0.f);
}

template<int I, int O, int IC>
__global__ __launch_bounds__(O, 2)
void edge_msg_acc(const float* __restrict__ h, const float* __restrict__ ea,
                  const float* __restrict__ W, const float* __restrict__ bias,
                  const float* __restrict__ root, float* __restrict__ agg)
{
    constexpr int K4 = IC / 4;
    const int d  = blockIdx.x;
    const int c  = blockIdx.y;
    const int i0 = c * IC;
    const int o  = threadIdx.x;

    __shared__ __align__(16) float hs[35][IC];
    __shared__ float4 as[34];

    if (o < 35) {
        const int s = (o < 34) ? (o + (o >= d ? 1 : 0)) : d;
        const float4* hp = (const float4*)(h + (size_t)s * I + i0);
#pragma unroll
        for (int k = 0; k < K4; ++k) ((float4*)hs[o])[k] = hp[k];
    }
    if (o >= 64 && o < 98) {
        const int j = o - 64;
        const int s = j + (j >= d ? 1 : 0);
        as[j] = ((const float4*)ea)[s * 34 + (d < s ? d : d - 1)];
    }
    __syncthreads();

    float w0[IC], w1[IC], w2[IC], w3[IC], bb[IC], rr[IC];
#pragma unroll
    for (int i = 0; i < IC; ++i) {
        const size_t base = (size_t)(i0 + i) * O + o;
        w0[i] = W[0 * (size_t)I * O + base];
        w1[i] = W[1 * (size_t)I * O + base];
        w2[i] = W[2 * (size_t)I * O + base];
        w3[i] = W[3 * (size_t)I * O + base];
        bb[i] = bias[base];
        rr[i] = root[base];
    }
    float acc = 0.f;
#pragma unroll 2
    for (int j = 0; j < 34; ++j) {
        const float4 a = as[j];
#pragma unroll
        for (int k = 0; k < K4; ++k) {
            const float4 hv = ((const float4*)hs[j])[k];
            const float hm[4] = {hv.x, hv.y, hv.z, hv.w};
#pragma unroll
            for (int m = 0; m < 4; ++m) {
                const int i = k * 4 + m;
                float w = fmaf(a.x, w0[i], fmaf(a.y, w1[i],
                          fmaf(a.z, w2[i], fmaf(a.w, w3[i], bb[i]))));
                acc = fmaf(hm[m], fmaxf(w, 0.f), acc);
            }
        }
    }
    float racc = 0.f;
#pragma unroll
    for (int k = 0; k < K4; ++k) {
        const float4 hv = ((const float4*)hs[34])[k];
        const float hm[4] = {hv.x, hv.y, hv.z, hv.w};
#pragma unroll
        for (int m = 0; m < 4; ++m) racc = fmaf(hm[m], rr[k * 4 + m], racc);
    }
    atomicAdd(&agg[d * O + o], acc * (1.f / 34.f) + racc);
}

template<int O>
__global__ __launch_bounds__(O)
void act_kernel(const float* __restrict__ agg, const float* __restrict__ bias,
                float* __restrict__ hout)
{
    hout[blockIdx.x * O + threadIdx.x] =
        fmaxf(agg[blockIdx.x * O + threadIdx.x] + bias[threadIdx.x], 0.f);
}

__global__ void cbt_kernel(const float* __restrict__ h, float* __restrict__ out)
{
    const int idx = blockIdx.x * blockDim.x + threadIdx.x;
    if (idx >= NN * NN) return;
    const int a = idx / NN;
    const int i = idx % NN;
    float sum = 0.f;
#pragma unroll 8
    for (int f = 0; f < 128; ++f)
        sum += fabsf(h[i * 128 + f] - h[a * 128 + f]);
    out[idx] = sum;
}

extern "C" void kernel_launch(void* const* d_in, const int* in_sizes, int n_in,
                              void* d_out, int out_size, void* d_ws, size_t ws_size,
                              hipStream_t stream) {
    const float* x      = (const float*)d_in[0];
    const float* ea     = (const float*)d_in[1];
    const float* mlp1_w = (const float*)d_in[3];
    const float* mlp1_b = (const float*)d_in[4];
    const float* root1  = (const float*)d_in[5];
    const float* bias1  = (const float*)d_in[6];
    const float* mlp2_w = (const float*)d_in[7];
    const float* mlp2_b = (const float*)d_in[8];
    const float* root2  = (const float*)d_in[9];
    const float* bias2  = (const float*)d_in[10];
    const float* mlp3_w = (const float*)d_in[11];
    const float* mlp3_b = (const float*)d_in[12];
    const float* root3  = (const float*)d_in[13];
    const float* bias3  = (const float*)d_in[14];
    float* out = (float*)d_out;
    float* ws  = (float*)d_ws;

    // mega layout
    float* h1    = ws;                      // 17920
    float* part2 = h1 + 35 * 512 + 35 * 256 + 35 * 128;   // after h1,h2,h3
    float* part3 = part2 + (size_t)64 * 8960;
    // fallback layout (separate region after part3)
    float* fb    = part3 + (size_t)128 * 4480;
    float* agg2  = fb;                      // 35*256
    float* agg3  = agg2 + 35 * 256;         // 35*128
    float* fh2   = agg3 + 35 * 128;         // 35*256
    float* fh3   = fh2 + 35 * 256;          // 35*128

    void* args[] = {
        (void*)&x, (void*)&ea,
        (void*)&mlp1_w, (void*)&mlp1_b, (void*)&root1, (void*)&bias1,
        (void*)&mlp2_w, (void*)&mlp2_b, (void*)&root2, (void*)&bias2,
        (void*)&mlp3_w, (void*)&mlp3_b, (void*)&root3, (void*)&bias3,
        (void*)&out, (void*)&ws
    };
    hipError_t err = hipLaunchCooperativeKernel((void*)mega_kernel, dim3(256),
                                                dim3(512), args, 0, stream);
    if (err != hipSuccess) {
        // R4-proven separate-kernel path
        hipMemsetAsync(agg2, 0, (size_t)(35 * 256 + 35 * 128) * sizeof(float), stream);
        layer1_kernel<<<NN, 512, 0, stream>>>(x, ea, mlp1_w, mlp1_b, root1, bias1, h1);
        edge_msg_acc<512, 256, 16><<<dim3(NN, 32), 256, 0, stream>>>(h1, ea, mlp2_w, mlp2_b, root2, agg2);
        act_kernel<256><<<NN, 256, 0, stream>>>(agg2, bias2, fh2);
        edge_msg_acc<256, 128, 8><<<dim3(NN, 32), 128, 0, stream>>>(fh2, ea, mlp3_w, mlp3_b, root3, agg3);
        act_kernel<128><<<NN, 128, 0, stream>>>(agg3, bias3, fh3);
        cbt_kernel<<<(NN * NN + 255) / 256, 256, 0, stream>>>(fh3, out);
    }
}

// Round 9
// 132.300 us; speedup vs baseline: 2.2561x; 2.2561x over previous
//
#include <hip/hip_runtime.h>

#define NN 35

// ws layout (floats): agg2[35*256] | agg3[35*128] (contiguous, zeroed by layer1) | h1[35*512]

// ---------------- Kernel 1: layer 1 (1 -> 512) + zero agg2/agg3 ----------------
__global__ __launch_bounds__(512)
void layer1_kernel(const float* __restrict__ x,      // [35,1]
                   const float* __restrict__ ea,     // [1190,4]
                   const float* __restrict__ W1, const float* __restrict__ b1,
                   const float* __restrict__ root1, const float* __restrict__ bias1,
                   float* __restrict__ h1,           // [35,512]
                   float* __restrict__ aggz)         // agg2..agg3, 35*384 floats
{
    const int d = blockIdx.x;
    const int o = threadIdx.x;
    const int gtid = d * 512 + o;
    if (gtid < 35 * 384) aggz[gtid] = 0.f;

    const float w0 = W1[o], w1 = W1[512 + o], w2 = W1[1024 + o], w3 = W1[1536 + o];
    const float bb = b1[o];
    float sum = 0.f;
#pragma unroll
    for (int s = 0; s < NN; ++s) {
        if (s == d) continue;
        const float4 a = ((const float4*)ea)[s * 34 + (d < s ? d : d - 1)];
        float w = fmaf(a.x, w0, fmaf(a.y, w1, fmaf(a.z, w2, fmaf(a.w, w3, bb))));
        sum = fmaf(x[s], fmaxf(w, 0.f), sum);
    }
    h1[gtid] = fmaxf(sum * (1.f / 34.f) + x[d] * root1[o] + bias1[o], 0.f);
}

// ---------------- Kernel 2: layer 2 edge+root, dst-major (R4-proven) ----------------
// Block (d, c): all 34 incoming edges for i-chunk c (IC=16) + root partial.
__global__ __launch_bounds__(256, 2)
void edge2_kernel(const float* __restrict__ h,     // [35, 512]
                  const float* __restrict__ ea,    // [1190,4]
                  const float* __restrict__ W,     // [4, 512*256]
                  const float* __restrict__ bias,  // [512*256]
                  const float* __restrict__ root,  // [512, 256]
                  float* __restrict__ agg)         // [35, 256]
{
    const int d  = blockIdx.x;
    const int c  = blockIdx.y;
    const int i0 = c * 16;
    const int o  = threadIdx.x;

    __shared__ __align__(16) float hs[35][16];
    __shared__ float4 as[34];

    if (o < 35) {
        const int s = (o < 34) ? (o + (o >= d ? 1 : 0)) : d;   // row 34 = d itself
        const float4* hp = (const float4*)(h + (size_t)s * 512 + i0);
#pragma unroll
        for (int k = 0; k < 4; ++k) ((float4*)hs[o])[k] = hp[k];
    }
    if (o >= 64 && o < 98) {
        const int j = o - 64;
        const int s = j + (j >= d ? 1 : 0);
        as[j] = ((const float4*)ea)[s * 34 + (d < s ? d : d - 1)];
    }
    __syncthreads();

    float w0[16], w1[16], w2[16], w3[16], bb[16], rr[16];
#pragma unroll
    for (int i = 0; i < 16; ++i) {
        const size_t base = (size_t)(i0 + i) * 256 + o;
        w0[i] = W[base];
        w1[i] = W[131072 + base];
        w2[i] = W[262144 + base];
        w3[i] = W[393216 + base];
        bb[i] = bias[base];
        rr[i] = root[base];
    }
    float acc = 0.f;
#pragma unroll 2
    for (int j = 0; j < 34; ++j) {
        const float4 a = as[j];
#pragma unroll
        for (int k = 0; k < 4; ++k) {
            const float4 hv = ((const float4*)hs[j])[k];
            const float hm[4] = {hv.x, hv.y, hv.z, hv.w};
#pragma unroll
            for (int m = 0; m < 4; ++m) {
                const int i = k * 4 + m;
                float w = fmaf(a.x, w0[i], fmaf(a.y, w1[i],
                          fmaf(a.z, w2[i], fmaf(a.w, w3[i], bb[i]))));
                acc = fmaf(hm[m], fmaxf(w, 0.f), acc);
            }
        }
    }
    float racc = 0.f;
#pragma unroll
    for (int k = 0; k < 4; ++k) {
        const float4 hv = ((const float4*)hs[34])[k];
        const float hm[4] = {hv.x, hv.y, hv.z, hv.w};
#pragma unroll
        for (int m = 0; m < 4; ++m) racc = fmaf(hm[m], rr[k * 4 + m], racc);
    }
    atomicAdd(&agg[d * 256 + o], acc * (1.f / 34.f) + racc);
}

// ---------------- Kernel 3: layer 3 edge+root, act2 fused into staging ----------------
// Block (d, c): IC=8. Stages relu(agg2 + bias2) rows directly.
__global__ __launch_bounds__(128, 2)
void edge3_kernel(const float* __restrict__ agg2,  // [35, 256] (pre-activation)
                  const float* __restrict__ bias2, // [256]
                  const float* __restrict__ ea,    // [1190,4]
                  const float* __restrict__ W,     // [4, 256*128]
                  const float* __restrict__ bias,  // [256*128]
                  const float* __restrict__ root,  // [256, 128]
                  float* __restrict__ agg)         // [35, 128]
{
    const int d  = blockIdx.x;
    const int c  = blockIdx.y;
    const int i0 = c * 8;
    const int o  = threadIdx.x;

    __shared__ __align__(16) float hs[35][8];
    __shared__ float4 as[34];

    if (o < 70) {
        const int r = o >> 1, k = o & 1;
        const int s = (r < 34) ? (r + (r >= d ? 1 : 0)) : d;   // row 34 = d itself
        float4 v = ((const float4*)(agg2 + (size_t)s * 256 + i0))[k];
        const float4 bv = ((const float4*)(bias2 + i0))[k];
        v.x = fmaxf(v.x + bv.x, 0.f);
        v.y = fmaxf(v.y + bv.y, 0.f);
        v.z = fmaxf(v.z + bv.z, 0.f);
        v.w = fmaxf(v.w + bv.w, 0.f);
        ((float4*)hs[r])[k] = v;
    }
    if (o >= 94) {
        const int j = o - 94;
        const int s = j + (j >= d ? 1 : 0);
        as[j] = ((const float4*)ea)[s * 34 + (d < s ? d : d - 1)];
    }
    __syncthreads();

    float w0[8], w1[8], w2[8], w3[8], bb[8], rr[8];
#pragma unroll
    for (int i = 0; i < 8; ++i) {
        const size_t base = (size_t)(i0 + i) * 128 + o;
        w0[i] = W[base];
        w1[i] = W[32768 + base];
        w2[i] = W[65536 + base];
        w3[i] = W[98304 + base];
        bb[i] = bias[base];
        rr[i] = root[base];
    }
    float acc = 0.f;
#pragma unroll 2
    for (int j = 0; j < 34; ++j) {
        const float4 a = as[j];
#pragma unroll
        for (int k = 0; k < 2; ++k) {
            const float4 hv = ((const float4*)hs[j])[k];
            const float hm[4] = {hv.x, hv.y, hv.z, hv.w};
#pragma unroll
            for (int m = 0; m < 4; ++m) {
                const int i = k * 4 + m;
                float w = fmaf(a.x, w0[i], fmaf(a.y, w1[i],
                          fmaf(a.z, w2[i], fmaf(a.w, w3[i], bb[i]))));
                acc = fmaf(hm[m], fmaxf(w, 0.f), acc);
            }
        }
    }
    float racc = 0.f;
#pragma unroll
    for (int k = 0; k < 2; ++k) {
        const float4 hv = ((const float4*)hs[34])[k];
        const float hm[4] = {hv.x, hv.y, hv.z, hv.w};
#pragma unroll
        for (int m = 0; m < 4; ++m) racc = fmaf(hm[m], rr[k * 4 + m], racc);
    }
    atomicAdd(&agg[d * 128 + o], acc * (1.f / 34.f) + racc);
}

// ---------------- Kernel 4: pairwise L1, act3 fused; one wave per pair ----------------
__global__ __launch_bounds__(256)
void cbt_kernel(const float* __restrict__ agg3,  // [35, 128] (pre-activation)
                const float* __restrict__ bias3, // [128]
                float* __restrict__ out)         // [35,35]
{
    const int wv = blockIdx.x * 4 + (threadIdx.x >> 6);
    const int lane = threadIdx.x & 63;
    if (wv >= NN * NN) return;
    const int a_ = wv / NN, i_ = wv % NN;
    float s = 0.f;
#pragma unroll
    for (int q = 0; q < 2; ++q) {
        const int f = lane + q * 64;
        const float bb = bias3[f];
        const float hi = fmaxf(agg3[i_ * 128 + f] + bb, 0.f);
        const float ha = fmaxf(agg3[a_ * 128 + f] + bb, 0.f);
        s += fabsf(hi - ha);
    }
#pragma unroll
    for (int off = 32; off > 0; off >>= 1)
        s += __shfl_xor(s, off, 64);
    if (lane == 0) out[wv] = s;
}

extern "C" void kernel_launch(void* const* d_in, const int* in_sizes, int n_in,
                              void* d_out, int out_size, void* d_ws, size_t ws_size,
                              hipStream_t stream) {
    const float* x      = (const float*)d_in[0];
    const float* ea     = (const float*)d_in[1];
    const float* mlp1_w = (const float*)d_in[3];
    const float* mlp1_b = (const float*)d_in[4];
    const float* root1  = (const float*)d_in[5];
    const float* bias1  = (const float*)d_in[6];
    const float* mlp2_w = (const float*)d_in[7];
    const float* mlp2_b = (const float*)d_in[8];
    const float* root2  = (const float*)d_in[9];
    const float* bias2  = (const float*)d_in[10];
    const float* mlp3_w = (const float*)d_in[11];
    const float* mlp3_b = (const float*)d_in[12];
    const float* root3  = (const float*)d_in[13];
    const float* bias3  = (const float*)d_in[14];
    float* out = (float*)d_out;

    float* ws   = (float*)d_ws;
    float* agg2 = ws;                  // 35*256
    float* agg3 = agg2 + 35 * 256;     // 35*128 (contiguous with agg2)
    float* h1   = agg3 + 35 * 128;     // 35*512

    // 1: layer 1 + zero aggs
    layer1_kernel<<<NN, 512, 0, stream>>>(x, ea, mlp1_w, mlp1_b, root1, bias1, h1, agg2);
    // 2: layer 2 (512 -> 256)
    edge2_kernel<<<dim3(NN, 32), 256, 0, stream>>>(h1, ea, mlp2_w, mlp2_b, root2, agg2);
    // 3: layer 3 (256 -> 128), act2 fused
    edge3_kernel<<<dim3(NN, 32), 128, 0, stream>>>(agg2, bias2, ea, mlp3_w, mlp3_b, root3, agg3);
    // 4: pairwise L1, act3 fused (1225 waves)
    cbt_kernel<<<(NN * NN + 3) / 4, 256, 0, stream>>>(agg3, bias3, out);
}